// Round 2
// baseline (1055.042 us; speedup 1.0000x reference)
//
#include <hip/hip_runtime.h>

#define NN   12000
#define NE   384000
#define FIN  512
#define FHID 256
#define FOUT 64

typedef unsigned short u16;
typedef __attribute__((ext_vector_type(8))) short  s8v;   // 8 x bf16 (4 VGPRs) MFMA operand
typedef __attribute__((ext_vector_type(4))) float  f4v;   // MFMA accumulator / float4

__device__ __forceinline__ u16 f2bf(float f) {
    union { float f; unsigned int i; } v; v.f = f;
    return (u16)((v.i + 0x7FFFu + ((v.i >> 16) & 1u)) >> 16);   // RNE
}

// ---------------- graph preprocessing ----------------

__global__ void k_deg(const int* __restrict__ col, float* __restrict__ deg) {
    int e = blockIdx.x * 256 + threadIdx.x;
    if (e < NE) atomicAdd(&deg[col[e]], 1.0f);
}

// single-block scan of degrees -> CSR offsets; dinv = rsqrt(deg_edges + 1) (self-loop)
__global__ __launch_bounds__(1024) void k_scan(const float* __restrict__ deg,
                                               float* __restrict__ dinv,
                                               int* __restrict__ offs,
                                               int* __restrict__ cursor) {
    __shared__ int sh[1024];
    int tid = threadIdx.x;
    int base = tid * 12;
    int loc[12];
    int sum = 0;
    for (int j = 0; j < 12; j++) {
        int i = base + j;
        int d = (i < NN) ? (int)deg[i] : 0;
        loc[j] = sum;
        sum += d;
    }
    sh[tid] = sum;
    __syncthreads();
    for (int off = 1; off < 1024; off <<= 1) {
        int v = (tid >= off) ? sh[tid - off] : 0;
        __syncthreads();
        sh[tid] += v;
        __syncthreads();
    }
    int prev = (tid == 0) ? 0 : sh[tid - 1];
    for (int j = 0; j < 12; j++) {
        int i = base + j;
        if (i < NN) {
            int o = prev + loc[j];
            offs[i] = o;
            cursor[i] = o;
            dinv[i] = rsqrtf(deg[i] + 1.0f);
        }
    }
    if (tid == 0) offs[NN] = NE;
}

__global__ void k_fill(const int* __restrict__ row, const int* __restrict__ col,
                       int* __restrict__ cursor, int* __restrict__ csr) {
    int e = blockIdx.x * 256 + threadIdx.x;
    if (e < NE) {
        int c = col[e];
        int p = atomicAdd(&cursor[c], 1);
        csr[p] = row[e];
    }
}

// ---------------- weight repack: fp32 B[K][N] -> bf16 per-(tile,kstep,lane) 8-elem frags ----
__global__ void k_repack(const float* __restrict__ B, u16* __restrict__ Bp, int K, int N) {
    int idx = blockIdx.x * 256 + threadIdx.x;
    int total = (N >> 4) * (K >> 5) * 64;
    if (idx >= total) return;
    int l  = idx & 63;
    int ts = idx >> 6;
    int Ks = K >> 5;
    int s  = ts % Ks;
    int t  = ts / Ks;
    int q = l >> 4, r = l & 15;
    s8v v;
    #pragma unroll
    for (int j = 0; j < 8; j++)
        v[j] = (short)f2bf(B[(s * 32 + q * 8 + j) * N + t * 16 + r]);
    ((s8v*)Bp)[idx] = v;
}

// ---------------- GEMM: C[m][n] = dinv[m] * sum_k A[m][k]*B[k][n]; fp32 A/C, bf16 MFMA ----
template <int K, int N>
__global__ __launch_bounds__(256) void k_gemm(const float* __restrict__ A,
                                              const u16* __restrict__ Bp,
                                              const float* __restrict__ dinv,
                                              float* __restrict__ C) {
    constexpr int KS = K / 32;
    int wave = threadIdx.x >> 6, lane = threadIdx.x & 63;
    int q = lane >> 4, r = lane & 15;
    int row0 = blockIdx.x * 64 + wave * 16;
    if (row0 >= NN) return;                    // wave-uniform guard (NN % 16 == 0)
    int tb = blockIdx.y * 4;

    f4v acc[4];
    #pragma unroll
    for (int t = 0; t < 4; t++) acc[t] = (f4v){0.f, 0.f, 0.f, 0.f};

    const float* arow = A + (size_t)(row0 + r) * K + q * 8;
    #pragma unroll 4
    for (int s = 0; s < KS; s++) {
        f4v f0 = *(const f4v*)(arow + s * 32);
        f4v f1 = *(const f4v*)(arow + s * 32 + 4);
        s8v a;
        #pragma unroll
        for (int j = 0; j < 4; j++) { a[j] = (short)f2bf(f0[j]); a[4 + j] = (short)f2bf(f1[j]); }
        #pragma unroll
        for (int t = 0; t < 4; t++) {
            s8v b = *(const s8v*)(Bp + ((((size_t)(tb + t) * KS + s) * 64 + lane) << 3));
            acc[t] = __builtin_amdgcn_mfma_f32_16x16x32_bf16(a, b, acc[t], 0, 0, 0);
        }
    }
    float dv[4];
    #pragma unroll
    for (int rr = 0; rr < 4; rr++) dv[rr] = dinv[row0 + q * 4 + rr];
    #pragma unroll
    for (int t = 0; t < 4; t++) {
        int n = (tb + t) * 16 + r;
        #pragma unroll
        for (int rr = 0; rr < 4; rr++) {
            int m = row0 + q * 4 + rr;
            C[(size_t)m * N + n] = acc[t][rr] * dv[rr];
        }
    }
}

// ---------------- aggregation: out[c] = act(dinv[c]*(sum_{e->c} hw'[src] + hw'[c]) + b) ----
template <int FPL, bool RELU>   // features per lane (F = FPL*64), fp32 throughout
__global__ __launch_bounds__(256) void k_agg(const float* __restrict__ hw,
                                             const int* __restrict__ csr,
                                             const int* __restrict__ offs,
                                             const float* __restrict__ dinv,
                                             const float* __restrict__ bias,
                                             float* __restrict__ out) {
    constexpr int F = FPL * 64;
    int wg = (blockIdx.x * 256 + threadIdx.x) >> 6;
    if (wg >= NN) return;
    int lane = threadIdx.x & 63;
    int c = wg;

    float acc[FPL];
    {   // self-loop term
        const float* p = hw + (size_t)c * F + lane * FPL;
        if constexpr (FPL == 4) {
            f4v v = *(const f4v*)p;
            #pragma unroll
            for (int k = 0; k < 4; k++) acc[k] = v[k];
        } else {
            acc[0] = *p;
        }
    }
    int beg = offs[c], end = offs[c + 1];
    for (int e = beg; e < end; e += 64) {
        int nb = end - e; if (nb > 64) nb = 64;
        int myid = (e + lane < end) ? csr[e + lane] : 0;
        for (int j = 0; j < nb; j++) {
            int src = __shfl(myid, j, 64);
            const float* p = hw + (size_t)src * F + lane * FPL;
            if constexpr (FPL == 4) {
                f4v v = *(const f4v*)p;
                #pragma unroll
                for (int k = 0; k < 4; k++) acc[k] += v[k];
            } else {
                acc[0] += *p;
            }
        }
    }
    float dv = dinv[c];
    if constexpr (FPL == 4) {
        f4v ov;
        #pragma unroll
        for (int k = 0; k < 4; k++) {
            float val = acc[k] * dv + bias[lane * 4 + k];
            if (RELU) val = fmaxf(val, 0.f);
            ov[k] = val;
        }
        *(f4v*)(out + (size_t)c * F + lane * 4) = ov;
    } else {
        float val = acc[0] * dv + bias[lane];
        if (RELU) val = fmaxf(val, 0.f);
        out[(size_t)c * F + lane] = val;
    }
}

// ---------------- decoder: out = sigmoid(mu @ mu^T), fp32 in/out, bf16 MFMA ----------------
__global__ __launch_bounds__(256) void k_dec(const float* __restrict__ mu, float* __restrict__ out) {
    int wave = threadIdx.x >> 6, lane = threadIdx.x & 63;
    int q = lane >> 4, r = lane & 15;
    int row0 = blockIdx.y * 64 + wave * 16;
    if (row0 >= NN) return;
    int col0 = blockIdx.x * 64;

    s8v a0, a1;
    {
        const float* ap = mu + (size_t)(row0 + r) * FOUT + q * 8;
        f4v f0 = *(const f4v*)(ap);
        f4v f1 = *(const f4v*)(ap + 4);
        f4v f2 = *(const f4v*)(ap + 32);
        f4v f3 = *(const f4v*)(ap + 36);
        #pragma unroll
        for (int j = 0; j < 4; j++) {
            a0[j] = (short)f2bf(f0[j]); a0[4 + j] = (short)f2bf(f1[j]);
            a1[j] = (short)f2bf(f2[j]); a1[4 + j] = (short)f2bf(f3[j]);
        }
    }

    #pragma unroll
    for (int t = 0; t < 4; t++) {
        int n0 = col0 + t * 16;
        if (n0 >= NN) return;     // tiles increase monotonically
        s8v b0, b1;
        const float* bp = mu + (size_t)(n0 + r) * FOUT + q * 8;
        f4v f0 = *(const f4v*)(bp);
        f4v f1 = *(const f4v*)(bp + 4);
        f4v f2 = *(const f4v*)(bp + 32);
        f4v f3 = *(const f4v*)(bp + 36);
        #pragma unroll
        for (int j = 0; j < 4; j++) {
            b0[j] = (short)f2bf(f0[j]); b0[4 + j] = (short)f2bf(f1[j]);
            b1[j] = (short)f2bf(f2[j]); b1[4 + j] = (short)f2bf(f3[j]);
        }
        f4v acc = (f4v){0.f, 0.f, 0.f, 0.f};
        acc = __builtin_amdgcn_mfma_f32_16x16x32_bf16(a0, b0, acc, 0, 0, 0);
        acc = __builtin_amdgcn_mfma_f32_16x16x32_bf16(a1, b1, acc, 0, 0, 0);
        #pragma unroll
        for (int rr = 0; rr < 4; rr++) {
            int m = row0 + q * 4 + rr;
            float sg = 1.0f / (1.0f + __expf(-acc[rr]));
            out[(size_t)m * NN + (n0 + r)] = sg;
        }
    }
}

// ---------------- launch ----------------
extern "C" void kernel_launch(void* const* d_in, const int* in_sizes, int n_in,
                              void* d_out, int out_size, void* d_ws, size_t ws_size,
                              hipStream_t stream) {
    const float* x   = (const float*)d_in[0];
    const int*   ei  = (const int*)d_in[1];        // [2*E]: row then col
    const float* W1  = (const float*)d_in[2];
    const float* b1  = (const float*)d_in[3];
    const float* W2  = (const float*)d_in[4];
    const float* b2  = (const float*)d_in[5];
    const float* Wmu = (const float*)d_in[6];
    const float* bmu = (const float*)d_in[7];
    // d_in[8], d_in[9] (Wls, bls): dead — z = mu in eval mode.

    char* w = (char*)d_ws;
    size_t off = 0;
    auto alloc = [&](size_t bytes) {
        void* p = w + off;
        off = (off + bytes + 255) & ~(size_t)255;
        return p;
    };
    float* deg    = (float*)alloc(NN * 4);
    float* dinv   = (float*)alloc(NN * 4);
    int*   offs   = (int*)alloc((NN + 1) * 4);
    int*   cursor = (int*)alloc(NN * 4);
    int*   csr    = (int*)alloc(NE * 4);
    float* hw     = (float*)alloc((size_t)NN * FHID * 4);   // GEMM outputs (max width 256)
    float* hA     = (float*)alloc((size_t)NN * FHID * 4);
    float* hB     = (float*)alloc((size_t)NN * FHID * 4);
    float* muB    = (float*)alloc((size_t)NN * FOUT * 4);
    u16*   W1p    = (u16*)alloc((size_t)FIN * FHID * 2);
    u16*   W2p    = (u16*)alloc((size_t)FHID * FHID * 2);
    u16*   Wmp    = (u16*)alloc((size_t)FHID * FOUT * 2);

    const int* erow = ei;
    const int* ecol = ei + NE;

    hipMemsetAsync(deg, 0, NN * 4, stream);
    k_deg<<<(NE + 255) / 256, 256, 0, stream>>>(ecol, deg);
    k_scan<<<1, 1024, 0, stream>>>(deg, dinv, offs, cursor);
    k_fill<<<(NE + 255) / 256, 256, 0, stream>>>(erow, ecol, cursor, csr);

    k_repack<<<((FIN / 32) * (FHID / 16) * 64 + 255) / 256, 256, 0, stream>>>(W1, W1p, FIN, FHID);
    k_repack<<<((FHID / 32) * (FHID / 16) * 64 + 255) / 256, 256, 0, stream>>>(W2, W2p, FHID, FHID);
    k_repack<<<((FHID / 32) * (FOUT / 16) * 64 + 255) / 256, 256, 0, stream>>>(Wmu, Wmp, FHID, FOUT);

    dim3 blk(256);
    // layer 1: hw' = dinv .* (x @ W1); h1 = relu(dinv .* (gather-sum + self) + b1)
    k_gemm<FIN, FHID><<<dim3(188, FHID / 64), blk, 0, stream>>>(x, W1p, dinv, hw);
    k_agg<4, true><<<NN / 4, blk, 0, stream>>>(hw, csr, offs, dinv, b1, hA);
    // layer 2
    k_gemm<FHID, FHID><<<dim3(188, FHID / 64), blk, 0, stream>>>(hA, W2p, dinv, hw);
    k_agg<4, true><<<NN / 4, blk, 0, stream>>>(hw, csr, offs, dinv, b2, hB);
    // mu head
    k_gemm<FHID, FOUT><<<dim3(188, FOUT / 64), blk, 0, stream>>>(hB, Wmp, dinv, hw);
    k_agg<1, false><<<NN / 4, blk, 0, stream>>>(hw, csr, offs, dinv, bmu, muB);
    // decoder
    k_dec<<<dim3(188, 188), blk, 0, stream>>>(muB, (float*)d_out);
}